// Round 14
// baseline (29.281 us; speedup 1.0000x reference)
//
#include <hip/hip_runtime.h>
#include <math.h>

#define TT   256
#define TM1  255
#define QD   9
#define KD   5
#define NH   3
#define DD   15   // NH*KD
#define HID  75   // 5*DD
#define NR   18   // NH + DD reduce values

#define K2E  2.8853900817779268f   // 2*log2(e)
#define L2E  1.4426950408889634f   // log2(e)
#define INVK 0.34657359027997264f  // ln(2)/2 = 1/K2E

typedef float v2f __attribute__((ext_vector_type(2)));

__device__ __forceinline__ v2f v2splat(float s) { v2f r; r.x = s; r.y = s; return r; }

__device__ __forceinline__ float fast_rcp(float x) {
    return __builtin_amdgcn_rcpf(x);   // v_rcp_f32
}

__device__ __forceinline__ float exp2_raw(float x) {   // v_exp_f32: 2^x
    float r; asm("v_exp_f32 %0, %1" : "=v"(r) : "v"(x)); return r;
}

template<int CTRL>
__device__ __forceinline__ float dpp_add(float x) {
    int y = __builtin_amdgcn_update_dpp(0, __float_as_int(x), CTRL, 0xf, 0xf, true);
    return x + __int_as_float(y);
}

// full-rate VALU wave64 sum; result valid in lane 63
__device__ __forceinline__ float wave_sum63(float x) {
    x = dpp_add<0x111>(x);  // row_shr:1
    x = dpp_add<0x112>(x);  // row_shr:2
    x = dpp_add<0x114>(x);  // row_shr:4
    x = dpp_add<0x118>(x);  // row_shr:8
    x = dpp_add<0x142>(x);  // row_bcast:15
    x = dpp_add<0x143>(x);  // row_bcast:31
    return x;
}

__device__ __forceinline__ float bcast(float x, int l) {
    return __int_as_float(__builtin_amdgcn_readlane(__float_as_int(x), l));
}

__global__ __launch_bounds__(256)
void fused_block_kernel(const float* __restrict__ state,   // (32,256,7)
                        const float* __restrict__ action,  // (32,256,2)
                        const float* __restrict__ Wk,      // (15,5)
                        const float* __restrict__ Wq,      // (15,9)
                        const float* __restrict__ Wv,      // (15,5)
                        const float* __restrict__ att_bias,// (5)
                        const float* __restrict__ Wscore,  // (1,5)
                        const float* __restrict__ bscore,  // (1)
                        const float* __restrict__ g1,
                        const float* __restrict__ beta1,
                        const float* __restrict__ W1,      // (75,15)
                        const float* __restrict__ bff1,    // (75)
                        const float* __restrict__ W2,      // (15,75)
                        const float* __restrict__ bff2,    // (15)
                        const float* __restrict__ g2,
                        const float* __restrict__ beta2,
                        float* __restrict__ out)           // (32,256,15)
{
    const int tid  = threadIdx.x;
    const int lane = tid & 63;
    const int wv   = __builtin_amdgcn_readfirstlane(tid >> 6);  // 0..3, SGPR
    const int qloc = wv >> 1;                 // query within block (0,1)
    const int half = wv & 1;                  // neighbor half (0,1)
    const int qgrp = blockIdx.x * 2 + qloc;   // global query index (b*256+qi)
    const int b    = qgrp >> 8;
    const int qi   = qgrp & 255;              // uniform per wave

    // Wk rows + folded score weight, 32B rows for broadcast b128/b64 reads
    __shared__ __align__(16) float s_wk8[DD*8];   // [d][0..4]=Wk row, [d][5]=-K2E*wsc
    __shared__ float s_red[2][2][NR];             // [query][half][18] partials
    __shared__ float s_h[2][76];                  // per-query MLP hidden slice

    const float* __restrict__ sb  = state + (size_t)b*TT*7;
    const float* __restrict__ sti = sb + qi*7;   // uniform -> s_loads
    const float si0 = sti[0], si1 = sti[1], si2 = sti[2], si3 = sti[3];

    // ---- stage Wk table (480 B, once per block)
    if (tid < DD) {
        #pragma unroll
        for (int c = 0; c < KD; c++) s_wk8[tid*8+c] = Wk[tid*KD+c];
        s_wk8[tid*8+5] = -K2E * Wscore[tid % KD];
        s_wk8[tid*8+6] = 0.0f;
        s_wk8[tid*8+7] = 0.0f;
    }

    // ---- query projection (+att_bias folded) lanes 0..14; scaled by 2*log2e
    float qv = 0.0f;
    if (lane < DD) {
        float acc = att_bias[lane % KD];
        #pragma unroll
        for (int k = 0; k < 7; k++) acc = fmaf(Wq[lane*QD+k], sti[k], acc);
        acc = fmaf(Wq[lane*QD+7], action[((size_t)b*TT+qi)*2 + 0], acc);
        acc = fmaf(Wq[lane*QD+8], action[((size_t)b*TT+qi)*2 + 1], acc);
        qv = acc * K2E;
    }
    float qb2[DD];
    #pragma unroll
    for (int d = 0; d < DD; d++) qb2[d] = bcast(qv, d);

    // score constant in exp2 domain
    float Cn = bscore[0];
    #pragma unroll
    for (int kk = 0; kk < KD; kk++) Cn += Wscore[kk];
    const float C2 = L2E * Cn;

    __syncthreads();   // s_wk8 ready

    // ---- geometry: ONE v2f group (2 pairs) per thread; features pre-scaled K2E
    v2f F0, F1, F2, F3, F4, Cp;
    {
        const int mm0 = half*128 + lane;                 // <= 191, always valid idx
        const int mm1 = mm0 + 64;                        // <= 255
        const int jj0 = mm0 + (mm0 >= qi ? 1 : 0);       // <= 192
        int       jj1 = mm1 + (mm1 >= qi ? 1 : 0);
        jj1 = (jj1 < TT) ? jj1 : (TT-1);                 // clamp (one lane)
        const float* __restrict__ r0 = sb + jj0*7;
        const float* __restrict__ r1 = sb + jj1*7;

        v2f d0, d1, d2, d3, th;
        d0.x = r0[0]; d0.y = r1[0];
        d1.x = r0[1]; d1.y = r1[1];
        d2.x = r0[2]; d2.y = r1[2];
        d3.x = r0[3]; d3.y = r1[3];
        th.x = r0[6]; th.y = r1[6];
        d0 = d0 - v2splat(si0);
        d1 = d1 - v2splat(si1);
        d2 = d2 - v2splat(si2);
        d3 = d3 - v2splat(si3);

        // ref rotates by ang = pi/2 - theta_j: cos(ang)=sin(th), sin(ang)=cos(th)
        v2f cs, sn;
        cs.x = __sinf(th.x); cs.y = __sinf(th.y);   // native v_sin
        sn.x = __cosf(th.x); sn.y = __cosf(th.y);   // native v_cos

        v2f xr0 = d0*cs - d1*sn;
        v2f yr0 = d0*sn + d1*cs;
        v2f xr1 = d2*cs - d3*sn;
        v2f yr1 = d2*sn + d3*cs;
        v2f s2  = xr0*xr0 + yr0*yr0;
        s2.x = fmaxf(s2.x, 1e-12f);                 // NaN-proof (self-pair clamp)
        s2.y = fmaxf(s2.y, 1e-12f);
        v2f rinv;
        rinv.x = __builtin_amdgcn_rsqf(s2.x);
        rinv.y = __builtin_amdgcn_rsqf(s2.y);
        v2f r = s2 * rinv;
        // sigmoid(1-5(r-0.2)) = rcp(1 + exp2(5*log2e*r - 2*log2e))
        v2f ea;
        ea.x = exp2_raw(fmaf(7.213475204444817f, r.x, -2.8853900817779268f));
        ea.y = exp2_raw(fmaf(7.213475204444817f, r.y, -2.8853900817779268f));
        v2f rt;
        rt.x = fast_rcp(1.0f + ea.x);
        rt.y = fast_rcp(1.0f + ea.y);

        v2f t = v2splat(K2E) * rinv;
        F0 = t * xr0;
        F1 = t * yr0;
        F2 = v2splat(K2E) * xr1;
        F3 = v2splat(K2E) * yr1;
        F4 = v2splat(K2E) * rt;

        Cp.x = (mm0 < TM1) ? C2 : -100.0f;          // invalid pair -> p ~ 0
        Cp.y = (mm1 < TM1) ? C2 : -100.0f;
    }

    // ---- scores: Wk row broadcast from LDS, 3 independent h-chains
    float red[NR];
    #pragma unroll
    for (int n = 0; n < NR; n++) red[n] = 0.0f;

    #pragma unroll
    for (int h = 0; h < NH; h++) {
        v2f sc = Cp;
        #pragma unroll
        for (int kk = 0; kk < KD; kk++) {
            const int d = h*KD + kk;
            const float4 wA = *(const float4*)&s_wk8[d*8];     // w0..w3
            const float2 wB = *(const float2*)&s_wk8[d*8+4];   // w4, -K2E*wsc

            v2f a = v2splat(qb2[d]);
            a = a + v2splat(wA.x) * F0;   // contracts to v_pk_fma_f32
            a = a + v2splat(wA.y) * F1;
            a = a + v2splat(wA.z) * F2;
            a = a + v2splat(wA.w) * F3;
            a = a + v2splat(wB.x) * F4;
            v2f e, sg;
            e.x = exp2_raw(a.x);
            e.y = exp2_raw(a.y);
            sg.x = fast_rcp(e.x + 1.0f);
            sg.y = fast_rcp(e.y + 1.0f);
            // wsc*tanh(a_nat) = wsc - 2*wsc*sigma, folded into C2 / wB.y
            sc = sc + v2splat(wB.y) * sg;
        }
        v2f p;
        p.x = exp2_raw(sc.x);                       // bounded |sc| -> no max-sub
        p.y = exp2_raw(sc.y);
        red[h] += p.x + p.y;
        red[NH+h*KD+0] = fmaf(p.y, F0.y, fmaf(p.x, F0.x, red[NH+h*KD+0]));
        red[NH+h*KD+1] = fmaf(p.y, F1.y, fmaf(p.x, F1.x, red[NH+h*KD+1]));
        red[NH+h*KD+2] = fmaf(p.y, F2.y, fmaf(p.x, F2.x, red[NH+h*KD+2]));
        red[NH+h*KD+3] = fmaf(p.y, F3.y, fmaf(p.x, F3.x, red[NH+h*KD+3]));
        red[NH+h*KD+4] = fmaf(p.y, F4.y, fmaf(p.x, F4.x, red[NH+h*KD+4]));
    }

    // ---- per-wave dpp reduce, write partials, barrier; half-1 waves retire
    #pragma unroll
    for (int n = 0; n < NR; n++) red[n] = wave_sum63(red[n]);
    if (lane == 63) {
        #pragma unroll
        for (int n = 0; n < NR; n++) s_red[qloc][half][n] = red[n];
    }
    __syncthreads();
    if (half == 1) return;           // free SIMD slots for the epilogue waves

    // ---- combine halves (uniform LDS reads -> broadcast)
    float fin[NR];
    #pragma unroll
    for (int n = 0; n < NR; n++)
        fin[n] = s_red[qloc][0][n] + s_red[qloc][1][n];

    // ---- Wv projection (deferred, linear) + softmax normalize (lanes 0..14)
    // fin's value part carries factor K2E -> un-scale by INVK
    float xm = 0.0f;
    if (lane < DD) {
        const int h = lane / KD;
        float acc = 0.0f;
        #pragma unroll
        for (int c = 0; c < KD; c++) acc = fmaf(Wv[lane*KD+c], fin[NH+h*KD+c], acc);
        xm = acc * fast_rcp(fin[h]) * INVK;
    }

    // ---- LN1 across lanes 0..15 (lane 15 contributes 0)
    float s1 = xm, sq = xm*xm;
    #pragma unroll
    for (int off = 8; off >= 1; off >>= 1) {
        s1 += __shfl_xor(s1, off, 16);
        sq += __shfl_xor(sq, off, 16);
    }
    const float mu1   = s1 * (1.0f/DD);
    const float rstd1 = rsqrtf(sq * (1.0f/DD) - mu1*mu1 + 1e-5f);
    float xln = 0.0f;
    if (lane < DD) xln = (xm - mu1) * rstd1 * g1[lane] + beta1[lane];

    // broadcast LN1 output for the MLP
    float xs[DD];
    #pragma unroll
    for (int d = 0; d < DD; d++) xs[d] = bcast(xln, d);

    // ---- MLP layer 1: 75 hidden units over 64 lanes (lanes 0..10 do two)
    {
        float h0 = bff1[lane];
        #pragma unroll
        for (int k = 0; k < DD; k++) h0 = fmaf(W1[lane*DD+k], xs[k], h0);
        s_h[qloc][lane] = fmaxf(h0, 0.0f);
        if (lane < HID-64) {
            float h1 = bff1[lane+64];
            #pragma unroll
            for (int k = 0; k < DD; k++) h1 = fmaf(W1[(lane+64)*DD+k], xs[k], h1);
            s_h[qloc][lane+64] = fmaxf(h1, 0.0f);
        }
    }
    // same-wave LDS producer/consumer: compiler inserts lgkmcnt wait

    // ---- MLP layer 2: 3 chunks x 25 over lane groups, combine via shfl
    const int c2  = lane >> 4;               // 0..3
    const int d2c = lane & 15;
    const int cc  = (c2 < 3) ? c2 : 2;       // clamp for safe addressing
    const int dc  = (d2c < DD) ? d2c : 0;
    float acc2 = 0.0f;
    #pragma unroll
    for (int k = 0; k < 25; k++)
        acc2 = fmaf(W2[dc*HID + cc*25 + k], s_h[qloc][cc*25 + k], acc2);
    acc2 = (c2 < 3) ? acc2 : 0.0f;           // kill duplicated chunk
    acc2 += __shfl_xor(acc2, 16);
    acc2 += __shfl_xor(acc2, 32);            // lanes 0..15 hold full sums

    // ---- residual + LN2 + store
    float x2 = 0.0f;
    if (lane < DD) x2 = xln + bff2[lane] + acc2;   // residual uses post-LN1 x
    float t1 = x2, t2 = x2*x2;
    #pragma unroll
    for (int off = 8; off >= 1; off >>= 1) {
        t1 += __shfl_xor(t1, off, 16);
        t2 += __shfl_xor(t2, off, 16);
    }
    const float mu2   = t1 * (1.0f/DD);
    const float rstd2 = rsqrtf(t2 * (1.0f/DD) - mu2*mu2 + 1e-5f);
    if (lane < DD)
        out[(size_t)qgrp*DD + lane] = (x2 - mu2) * rstd2 * g2[lane] + beta2[lane];
}

extern "C" void kernel_launch(void* const* d_in, const int* in_sizes, int n_in,
                              void* d_out, int out_size, void* d_ws, size_t ws_size,
                              hipStream_t stream) {
    const float* state    = (const float*)d_in[0];
    const float* action   = (const float*)d_in[1];
    const float* Wk       = (const float*)d_in[2];
    const float* Wq       = (const float*)d_in[3];
    const float* Wv       = (const float*)d_in[4];
    const float* att_bias = (const float*)d_in[5];
    const float* Wscore   = (const float*)d_in[6];
    const float* bscore   = (const float*)d_in[7];
    const float* g1       = (const float*)d_in[8];
    const float* beta1    = (const float*)d_in[9];
    const float* W1       = (const float*)d_in[10];
    const float* bff1     = (const float*)d_in[11];
    const float* W2       = (const float*)d_in[12];
    const float* bff2     = (const float*)d_in[13];
    const float* g2       = (const float*)d_in[14];
    const float* beta2    = (const float*)d_in[15];
    float* out = (float*)d_out;

    dim3 grid(32 * 256 / 2);   // 2 queries per block, 2 waves per query
    dim3 block(256);
    fused_block_kernel<<<grid, block, 0, stream>>>(
        state, action, Wk, Wq, Wv, att_bias, Wscore, bscore,
        g1, beta1, W1, bff1, W2, bff2, g2, beta2, out);
}

// Round 15
// 26.835 us; speedup vs baseline: 1.0911x; 1.0911x over previous
//
#include <hip/hip_runtime.h>
#include <math.h>

#define TT   256
#define TM1  255
#define QD   9
#define KD   5
#define NH   3
#define DD   15   // NH*KD
#define HID  75   // 5*DD
#define NR   18   // NH + DD reduce values

#define K2E  2.8853900817779268f   // 2*log2(e)
#define L2E  1.4426950408889634f   // log2(e)
#define INVK 0.34657359027997264f  // ln(2)/2 = 1/K2E

typedef float v2f __attribute__((ext_vector_type(2)));

__device__ __forceinline__ v2f v2splat(float s) { v2f r; r.x = s; r.y = s; return r; }

__device__ __forceinline__ float fast_rcp(float x) {
    return __builtin_amdgcn_rcpf(x);   // v_rcp_f32
}

__device__ __forceinline__ float exp2_raw(float x) {   // v_exp_f32: 2^x
    float r; asm("v_exp_f32 %0, %1" : "=v"(r) : "v"(x)); return r;
}

template<int CTRL>
__device__ __forceinline__ float dpp_add(float x) {
    int y = __builtin_amdgcn_update_dpp(0, __float_as_int(x), CTRL, 0xf, 0xf, true);
    return x + __int_as_float(y);
}

// full-rate VALU wave64 sum; result valid in lane 63
__device__ __forceinline__ float wave_sum63(float x) {
    x = dpp_add<0x111>(x);  // row_shr:1
    x = dpp_add<0x112>(x);  // row_shr:2
    x = dpp_add<0x114>(x);  // row_shr:4
    x = dpp_add<0x118>(x);  // row_shr:8
    x = dpp_add<0x142>(x);  // row_bcast:15
    x = dpp_add<0x143>(x);  // row_bcast:31
    return x;
}

__device__ __forceinline__ float bcast(float x, int l) {
    return __int_as_float(__builtin_amdgcn_readlane(__float_as_int(x), l));
}

__global__ __launch_bounds__(256, 8)   // register diet (~60 VGPR) + 8 waves/EU cap
void fused_block_kernel(const float* __restrict__ state,   // (32,256,7)
                        const float* __restrict__ action,  // (32,256,2)
                        const float* __restrict__ Wk,      // (15,5)
                        const float* __restrict__ Wq,      // (15,9)
                        const float* __restrict__ Wv,      // (15,5)
                        const float* __restrict__ att_bias,// (5)
                        const float* __restrict__ Wscore,  // (1,5)
                        const float* __restrict__ bscore,  // (1)
                        const float* __restrict__ g1,
                        const float* __restrict__ beta1,
                        const float* __restrict__ W1,      // (75,15)
                        const float* __restrict__ bff1,    // (75)
                        const float* __restrict__ W2,      // (15,75)
                        const float* __restrict__ bff2,    // (15)
                        const float* __restrict__ g2,
                        const float* __restrict__ beta2,
                        float* __restrict__ out)           // (32,256,15)
{
    const int tid  = threadIdx.x;
    const int lane = tid & 63;
    const int wv   = __builtin_amdgcn_readfirstlane(tid >> 6);  // SGPR wave id
    const int qgrp = blockIdx.x * 4 + wv;    // global query index (b*256+qi)
    const int b    = qgrp >> 8;
    const int qi   = qgrp & 255;             // uniform per wave

    // Wk rows + folded score weight, 32B rows for broadcast b128/b64 reads
    __shared__ __align__(16) float s_wk8[DD*8];   // [d][0..4]=Wk row, [d][5]=-K2E*wsc
    __shared__ float s_h[4][76];                  // per-wave MLP hidden slice

    const float* __restrict__ sb  = state + (size_t)b*TT*7;
    const float* __restrict__ sti = sb + qi*7;   // uniform -> s_loads
    const float si0 = sti[0], si1 = sti[1], si2 = sti[2], si3 = sti[3];

    // ---- stage Wk table (480 B, once per block)
    if (tid < DD) {
        #pragma unroll
        for (int c = 0; c < KD; c++) s_wk8[tid*8+c] = Wk[tid*KD+c];
        s_wk8[tid*8+5] = -K2E * Wscore[tid % KD];
        s_wk8[tid*8+6] = 0.0f;
        s_wk8[tid*8+7] = 0.0f;
    }

    // ---- query projection (+att_bias folded) lanes 0..14; scaled by 2*log2e
    float qv = 0.0f;
    if (lane < DD) {
        float acc = att_bias[lane % KD];
        #pragma unroll
        for (int k = 0; k < 7; k++) acc = fmaf(Wq[lane*QD+k], sti[k], acc);
        acc = fmaf(Wq[lane*QD+7], action[((size_t)b*TT+qi)*2 + 0], acc);
        acc = fmaf(Wq[lane*QD+8], action[((size_t)b*TT+qi)*2 + 1], acc);
        qv = acc * K2E;
    }
    float qb2[DD];                            // uniform -> SGPRs via readlane
    #pragma unroll
    for (int d = 0; d < DD; d++) qb2[d] = bcast(qv, d);

    // score constant in exp2 domain
    float Cn = bscore[0];
    #pragma unroll
    for (int kk = 0; kk < KD; kk++) Cn += Wscore[kk];
    const float C2 = L2E * Cn;

    __syncthreads();

    // ---- geometry for all 4 pairs (two v2f groups), features pre-scaled by K2E
    v2f F0[2], F1[2], F2[2], F3[2], F4[2], Cp[2];
    #pragma unroll
    for (int g = 0; g < 2; g++) {
        const int mm0 = lane + g*128;
        const int mm1 = mm0 + 64;
        const int jj0 = mm0 + (mm0 >= qi ? 1 : 0);       // always <= 255
        int       jj1 = mm1 + (mm1 >= qi ? 1 : 0);
        jj1 = (jj1 < TT) ? jj1 : (TT-1);                 // clamp (one lane, g=1)
        const float* __restrict__ r0 = sb + jj0*7;
        const float* __restrict__ r1 = sb + jj1*7;

        v2f d0, d1, d2, d3, th;
        d0.x = r0[0]; d0.y = r1[0];
        d1.x = r0[1]; d1.y = r1[1];
        d2.x = r0[2]; d2.y = r1[2];
        d3.x = r0[3]; d3.y = r1[3];
        th.x = r0[6]; th.y = r1[6];
        d0 = d0 - v2splat(si0);
        d1 = d1 - v2splat(si1);
        d2 = d2 - v2splat(si2);
        d3 = d3 - v2splat(si3);

        // ref rotates by ang = pi/2 - theta_j: cos(ang)=sin(th), sin(ang)=cos(th)
        v2f cs, sn;
        cs.x = __sinf(th.x); cs.y = __sinf(th.y);   // native v_sin
        sn.x = __cosf(th.x); sn.y = __cosf(th.y);   // native v_cos

        v2f xr0 = d0*cs - d1*sn;
        v2f yr0 = d0*sn + d1*cs;
        v2f xr1 = d2*cs - d3*sn;
        v2f yr1 = d2*sn + d3*cs;
        v2f s2  = xr0*xr0 + yr0*yr0;
        s2.x = fmaxf(s2.x, 1e-12f);                 // NaN-proof (self-pair clamp)
        s2.y = fmaxf(s2.y, 1e-12f);
        v2f rinv;
        rinv.x = __builtin_amdgcn_rsqf(s2.x);
        rinv.y = __builtin_amdgcn_rsqf(s2.y);
        v2f r = s2 * rinv;
        // sigmoid(1-5(r-0.2)) = rcp(1 + exp2(5*log2e*r - 2*log2e))
        v2f ea;
        ea.x = exp2_raw(fmaf(7.213475204444817f, r.x, -2.8853900817779268f));
        ea.y = exp2_raw(fmaf(7.213475204444817f, r.y, -2.8853900817779268f));
        v2f rt;
        rt.x = fast_rcp(1.0f + ea.x);
        rt.y = fast_rcp(1.0f + ea.y);

        v2f t  = v2splat(K2E) * rinv;
        F0[g] = t * xr0;
        F1[g] = t * yr0;
        F2[g] = v2splat(K2E) * xr1;
        F3[g] = v2splat(K2E) * yr1;
        F4[g] = v2splat(K2E) * rt;

        Cp[g].x = (mm0 < TM1) ? C2 : -100.0f;       // invalid pair -> p ~ 0
        Cp[g].y = (mm1 < TM1) ? C2 : -100.0f;
    }

    // ---- scores: Wk row broadcast from LDS once per (h,kk); groups interleaved;
    //      SCALAR accumulators (18 VGPR, not 36)
    float red[NR];
    #pragma unroll
    for (int n = 0; n < NR; n++) red[n] = 0.0f;

    #pragma unroll
    for (int h = 0; h < NH; h++) {
        v2f sc0 = Cp[0], sc1 = Cp[1];
        #pragma unroll
        for (int kk = 0; kk < KD; kk++) {
            const int d = h*KD + kk;
            const float4 wA = *(const float4*)&s_wk8[d*8];     // w0..w3
            const float2 wB = *(const float2*)&s_wk8[d*8+4];   // w4, -K2E*wsc
            const float qd = qb2[d];

            v2f a0 = v2splat(qd);
            a0 = a0 + v2splat(wA.x) * F0[0];   // contracts to v_pk_fma_f32
            a0 = a0 + v2splat(wA.y) * F1[0];
            a0 = a0 + v2splat(wA.z) * F2[0];
            a0 = a0 + v2splat(wA.w) * F3[0];
            a0 = a0 + v2splat(wB.x) * F4[0];
            v2f a1 = v2splat(qd);
            a1 = a1 + v2splat(wA.x) * F0[1];
            a1 = a1 + v2splat(wA.y) * F1[1];
            a1 = a1 + v2splat(wA.z) * F2[1];
            a1 = a1 + v2splat(wA.w) * F3[1];
            a1 = a1 + v2splat(wB.x) * F4[1];

            v2f e0, e1, sg0, sg1;
            e0.x = exp2_raw(a0.x); e0.y = exp2_raw(a0.y);
            e1.x = exp2_raw(a1.x); e1.y = exp2_raw(a1.y);
            sg0.x = fast_rcp(e0.x + 1.0f); sg0.y = fast_rcp(e0.y + 1.0f);
            sg1.x = fast_rcp(e1.x + 1.0f); sg1.y = fast_rcp(e1.y + 1.0f);
            // wsc*tanh(a_nat) = wsc - 2*wsc*sigma, folded into C2 / wB.y
            sc0 = sc0 + v2splat(wB.y) * sg0;
            sc1 = sc1 + v2splat(wB.y) * sg1;
        }
        v2f p0, p1;
        p0.x = exp2_raw(sc0.x); p0.y = exp2_raw(sc0.y);   // bounded -> no max-sub
        p1.x = exp2_raw(sc1.x); p1.y = exp2_raw(sc1.y);
        red[h] += (p0.x + p0.y) + (p1.x + p1.y);
        red[NH+h*KD+0] = fmaf(p1.y, F0[1].y, fmaf(p1.x, F0[1].x,
                         fmaf(p0.y, F0[0].y, fmaf(p0.x, F0[0].x, red[NH+h*KD+0]))));
        red[NH+h*KD+1] = fmaf(p1.y, F1[1].y, fmaf(p1.x, F1[1].x,
                         fmaf(p0.y, F1[0].y, fmaf(p0.x, F1[0].x, red[NH+h*KD+1]))));
        red[NH+h*KD+2] = fmaf(p1.y, F2[1].y, fmaf(p1.x, F2[1].x,
                         fmaf(p0.y, F2[0].y, fmaf(p0.x, F2[0].x, red[NH+h*KD+2]))));
        red[NH+h*KD+3] = fmaf(p1.y, F3[1].y, fmaf(p1.x, F3[1].x,
                         fmaf(p0.y, F3[0].y, fmaf(p0.x, F3[0].x, red[NH+h*KD+3]))));
        red[NH+h*KD+4] = fmaf(p1.y, F4[1].y, fmaf(p1.x, F4[1].x,
                         fmaf(p0.y, F4[0].y, fmaf(p0.x, F4[0].x, red[NH+h*KD+4]))));
    }

    // ---- single-wave reduction; broadcast totals IN PLACE (red reused as fin)
    #pragma unroll
    for (int n = 0; n < NR; n++) red[n] = wave_sum63(red[n]);
    #pragma unroll
    for (int n = 0; n < NR; n++) red[n] = bcast(red[n], 63);   // -> SGPRs

    // ---- Wv projection (deferred, linear) + softmax normalize (lanes 0..14)
    // value part carries factor K2E -> un-scale by INVK
    float xm = 0.0f;
    if (lane < DD) {
        const int h = lane / KD;
        float acc = 0.0f;
        #pragma unroll
        for (int c = 0; c < KD; c++) acc = fmaf(Wv[lane*KD+c], red[NH+h*KD+c], acc);
        xm = acc * fast_rcp(red[h]) * INVK;
    }

    // ---- LN1 across lanes 0..15 (lane 15 contributes 0)
    float s1 = xm, sq = xm*xm;
    #pragma unroll
    for (int off = 8; off >= 1; off >>= 1) {
        s1 += __shfl_xor(s1, off, 16);
        sq += __shfl_xor(sq, off, 16);
    }
    const float mu1   = s1 * (1.0f/DD);
    const float rstd1 = rsqrtf(sq * (1.0f/DD) - mu1*mu1 + 1e-5f);
    float xln = 0.0f;
    if (lane < DD) xln = (xm - mu1) * rstd1 * g1[lane] + beta1[lane];

    // broadcast LN1 output for the MLP (SGPRs)
    float xs[DD];
    #pragma unroll
    for (int d = 0; d < DD; d++) xs[d] = bcast(xln, d);

    // ---- MLP layer 1: 75 hidden units over 64 lanes (lanes 0..10 do two)
    {
        float h0 = bff1[lane];
        #pragma unroll
        for (int k = 0; k < DD; k++) h0 = fmaf(W1[lane*DD+k], xs[k], h0);
        s_h[wv][lane] = fmaxf(h0, 0.0f);
        if (lane < HID-64) {
            float h1 = bff1[lane+64];
            #pragma unroll
            for (int k = 0; k < DD; k++) h1 = fmaf(W1[(lane+64)*DD+k], xs[k], h1);
            s_h[wv][lane+64] = fmaxf(h1, 0.0f);
        }
    }
    // same-wave LDS producer/consumer: compiler inserts lgkmcnt wait

    // ---- MLP layer 2: 3 chunks x 25 over lane groups, combine via shfl
    const int c2  = lane >> 4;               // 0..3
    const int d2c = lane & 15;
    const int cc  = (c2 < 3) ? c2 : 2;       // clamp for safe addressing
    const int dc  = (d2c < DD) ? d2c : 0;
    float acc2 = 0.0f;
    #pragma unroll
    for (int k = 0; k < 25; k++)
        acc2 = fmaf(W2[dc*HID + cc*25 + k], s_h[wv][cc*25 + k], acc2);
    acc2 = (c2 < 3) ? acc2 : 0.0f;           // kill duplicated chunk
    acc2 += __shfl_xor(acc2, 16);
    acc2 += __shfl_xor(acc2, 32);            // lanes 0..15 hold full sums

    // ---- residual + LN2 + store
    float x2 = 0.0f;
    if (lane < DD) x2 = xln + bff2[lane] + acc2;   // residual uses post-LN1 x
    float t1 = x2, t2 = x2*x2;
    #pragma unroll
    for (int off = 8; off >= 1; off >>= 1) {
        t1 += __shfl_xor(t1, off, 16);
        t2 += __shfl_xor(t2, off, 16);
    }
    const float mu2   = t1 * (1.0f/DD);
    const float rstd2 = rsqrtf(t2 * (1.0f/DD) - mu2*mu2 + 1e-5f);
    if (lane < DD)
        out[(size_t)qgrp*DD + lane] = (x2 - mu2) * rstd2 * g2[lane] + beta2[lane];
}

extern "C" void kernel_launch(void* const* d_in, const int* in_sizes, int n_in,
                              void* d_out, int out_size, void* d_ws, size_t ws_size,
                              hipStream_t stream) {
    const float* state    = (const float*)d_in[0];
    const float* action   = (const float*)d_in[1];
    const float* Wk       = (const float*)d_in[2];
    const float* Wq       = (const float*)d_in[3];
    const float* Wv       = (const float*)d_in[4];
    const float* att_bias = (const float*)d_in[5];
    const float* Wscore   = (const float*)d_in[6];
    const float* bscore   = (const float*)d_in[7];
    const float* g1       = (const float*)d_in[8];
    const float* beta1    = (const float*)d_in[9];
    const float* W1       = (const float*)d_in[10];
    const float* bff1     = (const float*)d_in[11];
    const float* W2       = (const float*)d_in[12];
    const float* bff2     = (const float*)d_in[13];
    const float* g2       = (const float*)d_in[14];
    const float* beta2    = (const float*)d_in[15];
    float* out = (float*)d_out;

    dim3 grid(32 * 256 / 4);   // 4 queries (waves) per block
    dim3 block(256);
    fused_block_kernel<<<grid, block, 0, stream>>>(
        state, action, Wk, Wq, Wv, att_bias, Wscore, bscore,
        g1, beta1, W1, bff1, W2, bff2, g2, beta2, out);
}

// Round 16
// 24.913 us; speedup vs baseline: 1.1753x; 1.0772x over previous
//
#include <hip/hip_runtime.h>
#include <math.h>

#define TT   256
#define TM1  255
#define QD   9
#define KD   5
#define NH   3
#define DD   15   // NH*KD
#define HID  75   // 5*DD
#define NR   18   // NH + DD reduce values

#define K2E  2.8853900817779268f   // 2*log2(e)
#define L2E  1.4426950408889634f   // log2(e)
#define INVK 0.34657359027997264f  // ln(2)/2 = 1/K2E

typedef float v2f __attribute__((ext_vector_type(2)));

__device__ __forceinline__ v2f v2splat(float s) { v2f r; r.x = s; r.y = s; return r; }

__device__ __forceinline__ float fast_rcp(float x) {
    return __builtin_amdgcn_rcpf(x);   // v_rcp_f32
}

__device__ __forceinline__ float exp2_raw(float x) {   // v_exp_f32: 2^x
    float r; asm("v_exp_f32 %0, %1" : "=v"(r) : "v"(x)); return r;
}

template<int CTRL>
__device__ __forceinline__ float dpp_add(float x) {
    int y = __builtin_amdgcn_update_dpp(0, __float_as_int(x), CTRL, 0xf, 0xf, true);
    return x + __int_as_float(y);
}

// full-rate VALU wave64 sum; result valid in lane 63
__device__ __forceinline__ float wave_sum63(float x) {
    x = dpp_add<0x111>(x);  // row_shr:1
    x = dpp_add<0x112>(x);  // row_shr:2
    x = dpp_add<0x114>(x);  // row_shr:4
    x = dpp_add<0x118>(x);  // row_shr:8
    x = dpp_add<0x142>(x);  // row_bcast:15
    x = dpp_add<0x143>(x);  // row_bcast:31
    return x;
}

__device__ __forceinline__ float bcast(float x, int l) {
    return __int_as_float(__builtin_amdgcn_readlane(__float_as_int(x), l));
}

__global__ __launch_bounds__(256)
void fused_block_kernel(const float* __restrict__ state,   // (32,256,7)
                        const float* __restrict__ action,  // (32,256,2)
                        const float* __restrict__ Wk,      // (15,5)
                        const float* __restrict__ Wq,      // (15,9)
                        const float* __restrict__ Wv,      // (15,5)
                        const float* __restrict__ att_bias,// (5)
                        const float* __restrict__ Wscore,  // (1,5)
                        const float* __restrict__ bscore,  // (1)
                        const float* __restrict__ g1,
                        const float* __restrict__ beta1,
                        const float* __restrict__ W1,      // (75,15)
                        const float* __restrict__ bff1,    // (75)
                        const float* __restrict__ W2,      // (15,75)
                        const float* __restrict__ bff2,    // (15)
                        const float* __restrict__ g2,
                        const float* __restrict__ beta2,
                        float* __restrict__ out)           // (32,256,15)
{
    const int tid  = threadIdx.x;
    const int lane = tid & 63;
    const int wv   = __builtin_amdgcn_readfirstlane(tid >> 6);  // SGPR wave id
    const int qgrp = blockIdx.x * 4 + wv;    // global query index (b*256+qi)
    const int b    = qgrp >> 8;
    const int qi   = qgrp & 255;             // uniform per wave

    // Wk rows + folded score weight, 32B-aligned rows for b128/b64 broadcast reads
    __shared__ __align__(16) float s_wk8[DD*8];   // [d][0..4]=Wk row, [d][5]=-K2E*wsc
    __shared__ float s_h[4][76];                  // per-wave MLP hidden slice

    const float* __restrict__ sb  = state + (size_t)b*TT*7;
    const float* __restrict__ sti = sb + qi*7;   // uniform -> s_loads
    const float si0 = sti[0], si1 = sti[1], si2 = sti[2], si3 = sti[3];

    // ---- stage Wk table (480 B, once per block)
    if (tid < DD) {
        #pragma unroll
        for (int c = 0; c < KD; c++) s_wk8[tid*8+c] = Wk[tid*KD+c];
        s_wk8[tid*8+5] = -K2E * Wscore[tid % KD];
        s_wk8[tid*8+6] = 0.0f;
        s_wk8[tid*8+7] = 0.0f;
    }

    // ---- query projection (+att_bias folded) lanes 0..14; scaled by 2*log2e
    float qv = 0.0f;
    if (lane < DD) {
        float acc = att_bias[lane % KD];
        #pragma unroll
        for (int k = 0; k < 7; k++) acc = fmaf(Wq[lane*QD+k], sti[k], acc);
        acc = fmaf(Wq[lane*QD+7], action[((size_t)b*TT+qi)*2 + 0], acc);
        acc = fmaf(Wq[lane*QD+8], action[((size_t)b*TT+qi)*2 + 1], acc);
        qv = acc * K2E;
    }
    float qb2[DD];
    #pragma unroll
    for (int d = 0; d < DD; d++) qb2[d] = bcast(qv, d);

    // score constant in exp2 domain
    float Cn = bscore[0];
    #pragma unroll
    for (int kk = 0; kk < KD; kk++) Cn += Wscore[kk];
    const float C2 = L2E * Cn;

    __syncthreads();

    // ---- geometry for all 4 pairs (two v2f groups), features pre-scaled by K2E
    v2f F0[2], F1[2], F2[2], F3[2], F4[2], Cp[2];
    #pragma unroll
    for (int g = 0; g < 2; g++) {
        const int mm0 = lane + g*128;
        const int mm1 = mm0 + 64;
        const int jj0 = mm0 + (mm0 >= qi ? 1 : 0);       // always <= 255
        int       jj1 = mm1 + (mm1 >= qi ? 1 : 0);
        jj1 = (jj1 < TT) ? jj1 : (TT-1);                 // clamp (one lane, g=1)
        const float* __restrict__ r0 = sb + jj0*7;
        const float* __restrict__ r1 = sb + jj1*7;

        v2f d0, d1, d2, d3, th;
        d0.x = r0[0]; d0.y = r1[0];
        d1.x = r0[1]; d1.y = r1[1];
        d2.x = r0[2]; d2.y = r1[2];
        d3.x = r0[3]; d3.y = r1[3];
        th.x = r0[6]; th.y = r1[6];
        d0 = d0 - v2splat(si0);
        d1 = d1 - v2splat(si1);
        d2 = d2 - v2splat(si2);
        d3 = d3 - v2splat(si3);

        // ref rotates by ang = pi/2 - theta_j: cos(ang)=sin(th), sin(ang)=cos(th)
        v2f cs, sn;
        cs.x = __sinf(th.x); cs.y = __sinf(th.y);   // native v_sin
        sn.x = __cosf(th.x); sn.y = __cosf(th.y);   // native v_cos

        v2f xr0 = d0*cs - d1*sn;
        v2f yr0 = d0*sn + d1*cs;
        v2f xr1 = d2*cs - d3*sn;
        v2f yr1 = d2*sn + d3*cs;
        v2f s2  = xr0*xr0 + yr0*yr0;
        s2.x = fmaxf(s2.x, 1e-12f);                 // NaN-proof (self-pair clamp)
        s2.y = fmaxf(s2.y, 1e-12f);
        v2f rinv;
        rinv.x = __builtin_amdgcn_rsqf(s2.x);
        rinv.y = __builtin_amdgcn_rsqf(s2.y);
        v2f r = s2 * rinv;
        // sigmoid(1-5(r-0.2)) = rcp(1 + exp2(5*log2e*r - 2*log2e))
        v2f ea;
        ea.x = exp2_raw(fmaf(7.213475204444817f, r.x, -2.8853900817779268f));
        ea.y = exp2_raw(fmaf(7.213475204444817f, r.y, -2.8853900817779268f));
        v2f rt;
        rt.x = fast_rcp(1.0f + ea.x);
        rt.y = fast_rcp(1.0f + ea.y);

        v2f t = v2splat(K2E) * rinv;
        F0[g] = t * xr0;
        F1[g] = t * yr0;
        F2[g] = v2splat(K2E) * xr1;
        F3[g] = v2splat(K2E) * yr1;
        F4[g] = v2splat(K2E) * rt;

        Cp[g].x = (mm0 < TM1) ? C2 : -100.0f;       // invalid pair -> p ~ 0
        Cp[g].y = (mm1 < TM1) ? C2 : -100.0f;
    }

    // ---- scores: Wk row read ONCE per (h,kk) from LDS (broadcast), used by 4 pairs
    v2f rv[NR];
    #pragma unroll
    for (int n = 0; n < NR; n++) rv[n] = v2splat(0.0f);

    #pragma unroll
    for (int h = 0; h < NH; h++) {
        v2f sc0 = Cp[0], sc1 = Cp[1];
        #pragma unroll
        for (int kk = 0; kk < KD; kk++) {
            const int d = h*KD + kk;
            const float4 wA = *(const float4*)&s_wk8[d*8];     // w0..w3
            const float2 wB = *(const float2*)&s_wk8[d*8+4];   // w4, -K2E*wsc
            const float qd = qb2[d];

            v2f a0 = v2splat(qd);
            a0 = a0 + v2splat(wA.x) * F0[0];   // contracts to v_pk_fma_f32
            a0 = a0 + v2splat(wA.y) * F1[0];
            a0 = a0 + v2splat(wA.z) * F2[0];
            a0 = a0 + v2splat(wA.w) * F3[0];
            a0 = a0 + v2splat(wB.x) * F4[0];
            v2f a1 = v2splat(qd);
            a1 = a1 + v2splat(wA.x) * F0[1];
            a1 = a1 + v2splat(wA.y) * F1[1];
            a1 = a1 + v2splat(wA.z) * F2[1];
            a1 = a1 + v2splat(wA.w) * F3[1];
            a1 = a1 + v2splat(wB.x) * F4[1];

            v2f e0, e1, sg0, sg1;
            e0.x = exp2_raw(a0.x); e0.y = exp2_raw(a0.y);
            e1.x = exp2_raw(a1.x); e1.y = exp2_raw(a1.y);
            sg0.x = fast_rcp(e0.x + 1.0f); sg0.y = fast_rcp(e0.y + 1.0f);
            sg1.x = fast_rcp(e1.x + 1.0f); sg1.y = fast_rcp(e1.y + 1.0f);
            // wsc*tanh(a_nat) = wsc - 2*wsc*sigma, folded into C2 / wB.y
            sc0 = sc0 + v2splat(wB.y) * sg0;
            sc1 = sc1 + v2splat(wB.y) * sg1;
        }
        v2f p0, p1;
        p0.x = exp2_raw(sc0.x); p0.y = exp2_raw(sc0.y);   // bounded -> no max-sub
        p1.x = exp2_raw(sc1.x); p1.y = exp2_raw(sc1.y);
        rv[h] = rv[h] + p0 + p1;
        rv[NH+h*KD+0] = rv[NH+h*KD+0] + p0 * F0[0] + p1 * F0[1];
        rv[NH+h*KD+1] = rv[NH+h*KD+1] + p0 * F1[0] + p1 * F1[1];
        rv[NH+h*KD+2] = rv[NH+h*KD+2] + p0 * F2[0] + p1 * F2[1];
        rv[NH+h*KD+3] = rv[NH+h*KD+3] + p0 * F3[0] + p1 * F3[1];
        rv[NH+h*KD+4] = rv[NH+h*KD+4] + p0 * F4[0] + p1 * F4[1];
    }

    // ---- fold v2 accumulators, single-wave reduction + broadcast
    float red[NR];
    #pragma unroll
    for (int n = 0; n < NR; n++) red[n] = rv[n].x + rv[n].y;
    #pragma unroll
    for (int n = 0; n < NR; n++) red[n] = wave_sum63(red[n]);
    float fin[NR];
    #pragma unroll
    for (int n = 0; n < NR; n++) fin[n] = bcast(red[n], 63);

    // ---- Wv projection (deferred, linear) + softmax normalize (lanes 0..14)
    // fin's value part carries factor K2E -> un-scale by INVK
    float xm = 0.0f;
    if (lane < DD) {
        const int h = lane / KD;
        float acc = 0.0f;
        #pragma unroll
        for (int c = 0; c < KD; c++) acc = fmaf(Wv[lane*KD+c], fin[NH+h*KD+c], acc);
        xm = acc * fast_rcp(fin[h]) * INVK;
    }

    // ---- LN1 across lanes 0..15 (lane 15 contributes 0)
    float s1 = xm, sq = xm*xm;
    #pragma unroll
    for (int off = 8; off >= 1; off >>= 1) {
        s1 += __shfl_xor(s1, off, 16);
        sq += __shfl_xor(sq, off, 16);
    }
    const float mu1   = s1 * (1.0f/DD);
    const float rstd1 = rsqrtf(sq * (1.0f/DD) - mu1*mu1 + 1e-5f);
    float xln = 0.0f;
    if (lane < DD) xln = (xm - mu1) * rstd1 * g1[lane] + beta1[lane];

    // broadcast LN1 output for the MLP
    float xs[DD];
    #pragma unroll
    for (int d = 0; d < DD; d++) xs[d] = bcast(xln, d);

    // ---- MLP layer 1: 75 hidden units over 64 lanes (lanes 0..10 do two)
    {
        float h0 = bff1[lane];
        #pragma unroll
        for (int k = 0; k < DD; k++) h0 = fmaf(W1[lane*DD+k], xs[k], h0);
        s_h[wv][lane] = fmaxf(h0, 0.0f);
        if (lane < HID-64) {
            float h1 = bff1[lane+64];
            #pragma unroll
            for (int k = 0; k < DD; k++) h1 = fmaf(W1[(lane+64)*DD+k], xs[k], h1);
            s_h[wv][lane+64] = fmaxf(h1, 0.0f);
        }
    }
    // same-wave LDS producer/consumer: compiler inserts lgkmcnt wait

    // ---- MLP layer 2: 3 chunks x 25 over lane groups, combine via shfl
    const int c2  = lane >> 4;               // 0..3
    const int d2c = lane & 15;
    const int cc  = (c2 < 3) ? c2 : 2;       // clamp for safe addressing
    const int dc  = (d2c < DD) ? d2c : 0;
    float acc2 = 0.0f;
    #pragma unroll
    for (int k = 0; k < 25; k++)
        acc2 = fmaf(W2[dc*HID + cc*25 + k], s_h[wv][cc*25 + k], acc2);
    acc2 = (c2 < 3) ? acc2 : 0.0f;           // kill duplicated chunk
    acc2 += __shfl_xor(acc2, 16);
    acc2 += __shfl_xor(acc2, 32);            // lanes 0..15 hold full sums

    // ---- residual + LN2 + store
    float x2 = 0.0f;
    if (lane < DD) x2 = xln + bff2[lane] + acc2;   // residual uses post-LN1 x
    float t1 = x2, t2 = x2*x2;
    #pragma unroll
    for (int off = 8; off >= 1; off >>= 1) {
        t1 += __shfl_xor(t1, off, 16);
        t2 += __shfl_xor(t2, off, 16);
    }
    const float mu2   = t1 * (1.0f/DD);
    const float rstd2 = rsqrtf(t2 * (1.0f/DD) - mu2*mu2 + 1e-5f);
    if (lane < DD)
        out[(size_t)qgrp*DD + lane] = (x2 - mu2) * rstd2 * g2[lane] + beta2[lane];
}

extern "C" void kernel_launch(void* const* d_in, const int* in_sizes, int n_in,
                              void* d_out, int out_size, void* d_ws, size_t ws_size,
                              hipStream_t stream) {
    const float* state    = (const float*)d_in[0];
    const float* action   = (const float*)d_in[1];
    const float* Wk       = (const float*)d_in[2];
    const float* Wq       = (const float*)d_in[3];
    const float* Wv       = (const float*)d_in[4];
    const float* att_bias = (const float*)d_in[5];
    const float* Wscore   = (const float*)d_in[6];
    const float* bscore   = (const float*)d_in[7];
    const float* g1       = (const float*)d_in[8];
    const float* beta1    = (const float*)d_in[9];
    const float* W1       = (const float*)d_in[10];
    const float* bff1     = (const float*)d_in[11];
    const float* W2       = (const float*)d_in[12];
    const float* bff2     = (const float*)d_in[13];
    const float* g2       = (const float*)d_in[14];
    const float* beta2    = (const float*)d_in[15];
    float* out = (float*)d_out;

    dim3 grid(32 * 256 / 4);   // 4 queries (waves) per block
    dim3 block(256);
    fused_block_kernel<<<grid, block, 0, stream>>>(
        state, action, Wk, Wq, Wv, att_bias, Wscore, bscore,
        g1, beta1, W1, bff1, W2, bff2, g2, beta2, out);
}